// Round 1
// baseline (602.363 us; speedup 1.0000x reference)
//
#include <hip/hip_runtime.h>

typedef unsigned short u16;
typedef unsigned int u32;
typedef __attribute__((ext_vector_type(8))) short short8;
typedef __attribute__((ext_vector_type(4))) float f32x4;

// Bit-exact emulation of the reference's round-to-e4m3 on a pre-scaled value,
// returned as bf16 bits (exact: quantized values have <=4 significand bits).
// Reference: e = clip(floor(log2(max(|v|,2^-9))), -7, 8); q = round(|v|/2^e*8)/8*2^e
// Magic-add trick: s = 2^(e+20) => RNE to grid 2^(e-3); clamp s >= 2^13 realizes e>=-7.
__device__ __forceinline__ u16 quant_bf16(float v, float scale) {
  float sc = v * scale;
  sc = fminf(448.0f, fmaxf(-448.0f, sc));          // jnp.clip(x*scale, -448, 448)
  u32 b = __float_as_uint(sc);
  u32 sb = (b & 0x7f800000u) + 0x0A000000u;        // exponent bits + 20<<23
  sb = sb < 0x46000000u ? 0x46000000u : sb;        // s >= 2^13  (e clipped at -7)
  float mg = __uint_as_float(sb);
  float q = (fabsf(sc) + mg) - mg;                 // RNE onto the e4m3-emulated grid
  u32 qb = __float_as_uint(q) | (b & 0x80000000u); // restore sign
  return (u16)(qb >> 16);                          // exact bf16 (<=4 sig bits)
}

__global__ void init_ws(u32* w) {
  w[0] = 0u;
  w[1] = 0u;
}

__global__ void amax_kernel(const float4* __restrict__ p, int n4, u32* __restrict__ out) {
  float m = 0.0f;
  int idx = blockIdx.x * blockDim.x + threadIdx.x;
  int stride = gridDim.x * blockDim.x;
  for (int i = idx; i < n4; i += stride) {
    float4 v = p[i];
    m = fmaxf(m, fmaxf(fmaxf(fabsf(v.x), fabsf(v.y)), fmaxf(fabsf(v.z), fabsf(v.w))));
  }
#pragma unroll
  for (int off = 32; off > 0; off >>= 1)
    m = fmaxf(m, __shfl_down(m, off, 64));
  __shared__ float sm[4];
  int wv = threadIdx.x >> 6;
  if ((threadIdx.x & 63) == 0) sm[wv] = m;
  __syncthreads();
  if (threadIdx.x == 0) {
    float mm = fmaxf(fmaxf(sm[0], sm[1]), fmaxf(sm[2], sm[3]));
    atomicMax(out, __float_as_uint(mm));  // nonneg floats: uint order == float order
  }
}

__global__ void scales_kernel(const u32* __restrict__ am, float* __restrict__ wsf) {
  float ax = __uint_as_float(am[0]);
  float aw = __uint_as_float(am[1]);
  float sx = ax > 0.0f ? 448.0f / ax * 0.9f : 1.0f;  // exact op order of reference
  float sw = aw > 0.0f ? 448.0f / aw * 0.9f : 1.0f;
  wsf[2] = sx;
  wsf[3] = sw;
  wsf[4] = 1.0f / (sx * sw);
}

__global__ void quant_w_kernel(const float4* __restrict__ w, uint2* __restrict__ wq,
                               const float* __restrict__ wsf) {
  float sw = wsf[3];
  int i = blockIdx.x * blockDim.x + threadIdx.x;
  float4 v = w[i];
  uint2 r;
  r.x = (u32)quant_bf16(v.x, sw) | ((u32)quant_bf16(v.y, sw) << 16);
  r.y = (u32)quant_bf16(v.z, sw) | ((u32)quant_bf16(v.w, sw) << 16);
  wq[i] = r;
}

// C = (q(x) @ q(w)^T + bias) * inv. 128x128 block tile, BK=32, 256 threads (4 waves 2x2).
// w staged bf16 via global_load_lds(16B); x loaded fp32, quantized in-register, ds_write bf16.
__global__ void __launch_bounds__(256) gemm_kernel(const float* __restrict__ x,
                                                   const u16* __restrict__ wq,
                                                   const float* __restrict__ bias,
                                                   float* __restrict__ out,
                                                   const float* __restrict__ wsf) {
  __shared__ u16 As[128 * 32];  // [m][k] bf16
  __shared__ u16 Bs[128 * 32];  // [n][k] bf16
  const int tid = threadIdx.x;
  const int lane = tid & 63;
  const int wv = tid >> 6;
  const int quad = lane >> 4;
  const int lr = lane & 15;
  const int m0 = blockIdx.y * 128;
  const int n0 = blockIdx.x * 128;
  const float sx = wsf[2];
  const float inv = wsf[4];
  const int wm = (wv >> 1) * 64;
  const int wn = (wv & 1) * 64;
  const int xrow = tid >> 3;         // 0..31
  const int xcol = (tid & 7) * 4;    // 0..28 step 4

  f32x4 acc[4][4] = {};

  for (int kt = 0; kt < 16; ++kt) {
    __syncthreads();
    // ---- stage w tile [128][32] via async global->LDS (wave-uniform base + lane*16) ----
#pragma unroll
    for (int i = 0; i < 2; ++i) {
      const int c = wv + i * 4;                       // chunk 0..7, 16 rows each
      const int n = c * 16 + (lane >> 2);
      const u16* gp = wq + (size_t)(n0 + n) * 512 + kt * 32 + (lane & 3) * 8;
      u16* lp = &Bs[c * 512 + lane * 8];
      __builtin_amdgcn_global_load_lds((const __attribute__((address_space(1))) u32*)gp,
                                       (__attribute__((address_space(3))) u32*)lp, 16, 0, 0);
    }
    // ---- stage x tile [128][32]: fp32 load -> quantize -> bf16 ds_write ----
#pragma unroll
    for (int s = 0; s < 4; ++s) {
      const int r = s * 32 + xrow;
      const float4 v = *(const float4*)(x + (size_t)(m0 + r) * 512 + kt * 32 + xcol);
      uint2 pk;
      pk.x = (u32)quant_bf16(v.x, sx) | ((u32)quant_bf16(v.y, sx) << 16);
      pk.y = (u32)quant_bf16(v.z, sx) | ((u32)quant_bf16(v.w, sx) << 16);
      *(uint2*)&As[r * 32 + xcol] = pk;
    }
    __syncthreads();
    // ---- fragments + MFMA ----
    short8 af[4], bf[4];
#pragma unroll
    for (int mi = 0; mi < 4; ++mi)
      af[mi] = *(const short8*)&As[(wm + mi * 16 + lr) * 32 + quad * 8];
#pragma unroll
    for (int ni = 0; ni < 4; ++ni)
      bf[ni] = *(const short8*)&Bs[(wn + ni * 16 + lr) * 32 + quad * 8];
#pragma unroll
    for (int mi = 0; mi < 4; ++mi)
#pragma unroll
      for (int ni = 0; ni < 4; ++ni)
        acc[mi][ni] = __builtin_amdgcn_mfma_f32_16x16x32_bf16(af[mi], bf[ni], acc[mi][ni], 0, 0, 0);
  }

  // ---- epilogue: out = (acc + bias) * inv ; C layout col=lane&15, row=quad*4+reg ----
  float bn[4];
#pragma unroll
  for (int ni = 0; ni < 4; ++ni) bn[ni] = bias[n0 + wn + ni * 16 + lr];
#pragma unroll
  for (int mi = 0; mi < 4; ++mi) {
    const int gr = m0 + wm + mi * 16 + quad * 4;
#pragma unroll
    for (int ni = 0; ni < 4; ++ni) {
      const int gc = n0 + wn + ni * 16 + lr;
#pragma unroll
      for (int j = 0; j < 4; ++j)
        out[(size_t)(gr + j) * 512 + gc] = (acc[mi][ni][j] + bn[ni]) * inv;
    }
  }
}

extern "C" void kernel_launch(void* const* d_in, const int* in_sizes, int n_in,
                              void* d_out, int out_size, void* d_ws, size_t ws_size,
                              hipStream_t stream) {
  const float* x = (const float*)d_in[0];
  const float* w = (const float*)d_in[1];
  const float* bias = (const float*)d_in[2];
  float* out = (float*)d_out;

  const int K = 512, N = 512;
  const int M = in_sizes[0] / K;  // 131072

  u32* ws_u = (u32*)d_ws;
  float* ws_f = (float*)d_ws;
  u16* wq = (u16*)((char*)d_ws + 1024);  // 512 KB bf16 quantized weight

  hipLaunchKernelGGL(init_ws, dim3(1), dim3(1), 0, stream, ws_u);
  hipLaunchKernelGGL(amax_kernel, dim3(1024), dim3(256), 0, stream,
                     (const float4*)x, (M * K) / 4, ws_u + 0);
  hipLaunchKernelGGL(amax_kernel, dim3(64), dim3(256), 0, stream,
                     (const float4*)w, (N * K) / 4, ws_u + 1);
  hipLaunchKernelGGL(scales_kernel, dim3(1), dim3(1), 0, stream, ws_u, ws_f);
  hipLaunchKernelGGL(quant_w_kernel, dim3((N * K / 4) / 256), dim3(256), 0, stream,
                     (const float4*)w, (uint2*)wq, ws_f);
  // N-fast grid: the 4 blocks sharing an x row-tile run adjacently -> x re-reads hit L2/LLC
  hipLaunchKernelGGL(gemm_kernel, dim3(N / 128, M / 128), dim3(256), 0, stream,
                     x, wq, bias, out, ws_f);
}

// Round 2
// 555.226 us; speedup vs baseline: 1.0849x; 1.0849x over previous
//
#include <hip/hip_runtime.h>

typedef unsigned short u16;
typedef unsigned int u32;
typedef __attribute__((ext_vector_type(8))) short short8;
typedef __attribute__((ext_vector_type(4))) float f32x4;

// Bit-exact emulation of the reference's round-to-e4m3 on a pre-scaled value,
// returned as bf16 bits (exact: quantized values have <=4 significand bits).
// e = clip(floor(log2(max(|v|,2^-9))), -7, 8); q = round(|v|/2^e*8)/8*2^e
// Magic-add: s = 2^(e+20) => RNE to grid 2^(e-3); clamp s >= 2^13 realizes e>=-7.
__device__ __forceinline__ u16 quant_bf16(float v, float scale) {
  float sc = v * scale;
  sc = fminf(448.0f, fmaxf(-448.0f, sc));
  u32 b = __float_as_uint(sc);
  u32 sb = (b & 0x7f800000u) + 0x0A000000u;
  sb = sb < 0x46000000u ? 0x46000000u : sb;
  float mg = __uint_as_float(sb);
  float q = (fabsf(sc) + mg) - mg;
  u32 qb = __float_as_uint(q) | (b & 0x80000000u);
  return (u16)(qb >> 16);
}

__device__ __forceinline__ float block_max(float m) {
#pragma unroll
  for (int off = 32; off > 0; off >>= 1)
    m = fmaxf(m, __shfl_down(m, off, 64));
  __shared__ float sm[4];
  int wv = threadIdx.x >> 6;
  if ((threadIdx.x & 63) == 0) sm[wv] = m;
  __syncthreads();
  float r = fmaxf(fmaxf(sm[0], sm[1]), fmaxf(sm[2], sm[3]));
  __syncthreads();
  return r;
}

#define XBLOCKS 2048
#define WBLOCKS 64

// blocks [0,2048): amax partials over x; [2048,2112): over w. No atomics, no init.
__global__ void amax2_kernel(const float4* __restrict__ x, int nx4,
                             const float4* __restrict__ w, int nw4,
                             float* __restrict__ px, float* __restrict__ pw) {
  int bid = blockIdx.x;
  const float4* p;
  int n4, b, nb;
  float* dst;
  if (bid < XBLOCKS) { p = x; n4 = nx4; dst = px; b = bid; nb = XBLOCKS; }
  else { p = w; n4 = nw4; dst = pw; b = bid - XBLOCKS; nb = WBLOCKS; }
  float m = 0.0f;
  int stride = nb * 256;
  for (int i = b * 256 + threadIdx.x; i < n4; i += stride) {
    float4 v = p[i];
    m = fmaxf(m, fmaxf(fmaxf(fabsf(v.x), fabsf(v.y)), fmaxf(fabsf(v.z), fabsf(v.w))));
  }
  m = block_max(m);
  if (threadIdx.x == 0) dst[b] = m;
}

__global__ void scales_kernel(const float* __restrict__ px, const float* __restrict__ pw,
                              float* __restrict__ wsf) {
  int tid = threadIdx.x;
  float mx = 0.0f;
  for (int i = tid; i < XBLOCKS; i += 256) mx = fmaxf(mx, px[i]);
  mx = block_max(mx);
  float mw = tid < WBLOCKS ? pw[tid] : 0.0f;
  mw = block_max(mw);
  if (tid == 0) {
    float sx = mx > 0.0f ? 448.0f / mx * 0.9f : 1.0f;  // exact op order of reference
    float sw = mw > 0.0f ? 448.0f / mw * 0.9f : 1.0f;
    wsf[2] = sx;
    wsf[3] = sw;
    wsf[4] = 1.0f / (sx * sw);
  }
}

__global__ void quant_w_kernel(const float4* __restrict__ w, uint2* __restrict__ wq,
                               const float* __restrict__ wsf) {
  float sw = wsf[3];
  int i = blockIdx.x * blockDim.x + threadIdx.x;
  float4 v = w[i];
  uint2 r;
  r.x = (u32)quant_bf16(v.x, sw) | ((u32)quant_bf16(v.y, sw) << 16);
  r.y = (u32)quant_bf16(v.z, sw) | ((u32)quant_bf16(v.w, sw) << 16);
  wq[i] = r;
}

// C = (q(x) @ q(w)^T + bias) * inv.  BM=128, BN=256, BK=32, 256 thr (4 waves 2x2;
// wave computes 64x128 = 4x8 16x16 tiles). w staged bf16 via global_load_lds(16B);
// x loaded fp32 float4, quantized in-register, ds_write bf16.
// Grid: 1-D swizzled so the 2 blocks sharing an x row-tile have linear ids differing
// by 8 -> same XCD under round-robin dispatch -> 2nd x read hits that XCD's L2.
__global__ void __launch_bounds__(256, 2) gemm_kernel(const float* __restrict__ x,
                                                      const u16* __restrict__ wq,
                                                      const float* __restrict__ bias,
                                                      float* __restrict__ out,
                                                      const float* __restrict__ wsf) {
  __shared__ u16 As[128 * 32];  // [m][k] bf16
  __shared__ u16 Bs[256 * 32];  // [n][k] bf16
  const int tid = threadIdx.x;
  const int lane = tid & 63;
  const int wv = tid >> 6;
  const int quad = lane >> 4;
  const int lr = lane & 15;

  const int lin = blockIdx.x;
  const int xcd = lin & 7;
  const int jn = (lin >> 3) & 1;
  const int grp = lin >> 4;
  const int m0 = (grp * 8 + xcd) * 128;
  const int n0 = jn * 256;

  const float sx = wsf[2];
  const float inv = wsf[4];
  const int wm = (wv >> 1) * 64;
  const int wn = (wv & 1) * 128;
  const int xrow = tid >> 3;       // 0..31
  const int xcol = (tid & 7) * 4;  // 0..28 step 4

  f32x4 acc[4][8] = {};

  for (int kt = 0; kt < 16; ++kt) {
    __syncthreads();
    // ---- stage w tile [256][32] via async global->LDS (wave-uniform base + lane*16) ----
#pragma unroll
    for (int i = 0; i < 4; ++i) {
      const int c = wv + i * 4;  // chunk 0..15, 16 rows each
      const int n = c * 16 + (lane >> 2);
      const u16* gp = wq + (size_t)(n0 + n) * 512 + kt * 32 + (lane & 3) * 8;
      u16* lp = &Bs[c * 512 + lane * 8];
      __builtin_amdgcn_global_load_lds((const __attribute__((address_space(1))) u32*)gp,
                                       (__attribute__((address_space(3))) u32*)lp, 16, 0, 0);
    }
    // ---- stage x tile [128][32]: fp32 load -> quantize -> bf16 ds_write ----
#pragma unroll
    for (int s = 0; s < 4; ++s) {
      const int r = s * 32 + xrow;
      const float4 v = *(const float4*)(x + (size_t)(m0 + r) * 512 + kt * 32 + xcol);
      uint2 pk;
      pk.x = (u32)quant_bf16(v.x, sx) | ((u32)quant_bf16(v.y, sx) << 16);
      pk.y = (u32)quant_bf16(v.z, sx) | ((u32)quant_bf16(v.w, sx) << 16);
      *(uint2*)&As[r * 32 + xcol] = pk;
    }
    __syncthreads();
    // ---- fragments + MFMA ----
    short8 af[4], bf[8];
#pragma unroll
    for (int mi = 0; mi < 4; ++mi)
      af[mi] = *(const short8*)&As[(wm + mi * 16 + lr) * 32 + quad * 8];
#pragma unroll
    for (int ni = 0; ni < 8; ++ni)
      bf[ni] = *(const short8*)&Bs[(wn + ni * 16 + lr) * 32 + quad * 8];
#pragma unroll
    for (int mi = 0; mi < 4; ++mi)
#pragma unroll
      for (int ni = 0; ni < 8; ++ni)
        acc[mi][ni] = __builtin_amdgcn_mfma_f32_16x16x32_bf16(af[mi], bf[ni], acc[mi][ni], 0, 0, 0);
  }

  // ---- epilogue: out = (acc + bias) * inv ; C layout col=lane&15, row=quad*4+reg ----
  float bn[8];
#pragma unroll
  for (int ni = 0; ni < 8; ++ni) bn[ni] = bias[n0 + wn + ni * 16 + lr];
#pragma unroll
  for (int mi = 0; mi < 4; ++mi) {
    const int gr = m0 + wm + mi * 16 + quad * 4;
#pragma unroll
    for (int ni = 0; ni < 8; ++ni) {
      const int gc = n0 + wn + ni * 16 + lr;
#pragma unroll
      for (int j = 0; j < 4; ++j)
        out[(size_t)(gr + j) * 512 + gc] = (acc[mi][ni][j] + bn[ni]) * inv;
    }
  }
}

extern "C" void kernel_launch(void* const* d_in, const int* in_sizes, int n_in,
                              void* d_out, int out_size, void* d_ws, size_t ws_size,
                              hipStream_t stream) {
  const float* x = (const float*)d_in[0];
  const float* w = (const float*)d_in[1];
  const float* bias = (const float*)d_in[2];
  float* out = (float*)d_out;

  const int K = 512, N = 512;
  const int M = in_sizes[0] / K;  // 131072

  float* ws_f = (float*)d_ws;                  // [0..16) scalars
  float* px = ws_f + 16;                       // 2048 x-partials
  float* pw = ws_f + 16 + XBLOCKS;             // 64 w-partials
  u16* wq = (u16*)((char*)d_ws + 16384);       // 512 KB bf16 quantized weight

  hipLaunchKernelGGL(amax2_kernel, dim3(XBLOCKS + WBLOCKS), dim3(256), 0, stream,
                     (const float4*)x, (M * K) / 4, (const float4*)w, (N * K) / 4, px, pw);
  hipLaunchKernelGGL(scales_kernel, dim3(1), dim3(256), 0, stream, px, pw, ws_f);
  hipLaunchKernelGGL(quant_w_kernel, dim3((N * K / 4) / 256), dim3(256), 0, stream,
                     (const float4*)w, (uint2*)wq, ws_f);
  hipLaunchKernelGGL(gemm_kernel, dim3((M / 128) * 2), dim3(256), 0, stream,
                     x, wq, bias, out, ws_f);
}